// Round 6
// baseline (1389.584 us; speedup 1.0000x reference)
//
#include <hip/hip_runtime.h>
#include <stdint.h>

#define OUTF 4096
#define INF  4096
#define NBAT 2048
#define T_STEPS 128

typedef __attribute__((ext_vector_type(8))) short bf16x8;
typedef __attribute__((ext_vector_type(16))) float f32x16;
typedef __attribute__((ext_vector_type(4))) float f32x4;
typedef __attribute__((ext_vector_type(4))) unsigned int u32x4;
typedef const __attribute__((address_space(1))) uint8_t* gptr_t;
typedef __attribute__((address_space(3))) uint8_t* lptr_t;

__device__ __forceinline__ uint32_t f2bf(float f) {
  uint32_t u = __builtin_bit_cast(uint32_t, f);
  return (u + 0x7FFFu + ((u >> 16) & 1u)) >> 16;
}

// split two raw f32 words into packed bf16 hi-pair and lo-pair (lo = residual,
// truncated — error 2^-17 rel, negligible vs dropped lo*lo term)
__device__ __forceinline__ void split2(uint32_t u0, uint32_t u1,
                                       uint32_t& h, uint32_t& l) {
  uint32_t h0 = (u0 + 0x7FFFu + ((u0 >> 16) & 1u)) >> 16;
  uint32_t h1 = (u1 + 0x7FFFu + ((u1 >> 16) & 1u)) >> 16;
  float r0 = __builtin_bit_cast(float, u0) - __builtin_bit_cast(float, h0 << 16);
  float r1 = __builtin_bit_cast(float, u1) - __builtin_bit_cast(float, h1 << 16);
  h = h0 | (h1 << 16);
  l = (__builtin_bit_cast(uint32_t, r0) >> 16) |
      (__builtin_bit_cast(uint32_t, r1) & 0xFFFF0000u);
}

// ------------- fused: zero W (64MB) + transpose/split X (one launch) -----------
__global__ void zero_packX_kernel(uint4* __restrict__ W, const float* __restrict__ X,
                                  uint16_t* __restrict__ Xh, uint16_t* __restrict__ Xl) {
  unsigned bid = blockIdx.x;
  if (bid < 16384) {
    W[(size_t)bid * 256 + threadIdx.x] = make_uint4(0u, 0u, 0u, 0u);
    return;
  }
  bid -= 16384;
  __shared__ float t[32][33];
  int n0 = (bid & 63) * 32, k0 = (bid >> 6) * 32;
  int tx = threadIdx.x & 31, ty = threadIdx.x >> 5;  // 32 x 8
#pragma unroll
  for (int j = 0; j < 4; ++j)
    t[ty + j * 8][tx] = X[(size_t)(k0 + ty + j * 8) * NBAT + n0 + tx];
  __syncthreads();
#pragma unroll
  for (int j = 0; j < 4; ++j) {
    int n = n0 + ty + j * 8, k = k0 + tx;
    float f = t[tx][ty + j * 8];
    uint32_t hi = f2bf(f);
    float fhi = __builtin_bit_cast(float, hi << 16);
    uint32_t lo = f2bf(f - fhi);
    Xh[(size_t)n * INF + k] = (uint16_t)hi;
    Xl[(size_t)n * INF + k] = (uint16_t)lo;
  }
}

// ------------- COO scatter-add (sums duplicates, matches .at[].add) -------------
__global__ void scatter_kernel(const float* __restrict__ vals,
                               const int* __restrict__ rows,
                               const int* __restrict__ cols,
                               float* __restrict__ W, int nnz) {
  int i = blockIdx.x * blockDim.x + threadIdx.x;
  if (i < nnz) atomicAdd(&W[(size_t)rows[i] * INF + cols[i]], vals[i]);
}

// ------------- split-K split-bf16 GEMM ------------------------------------------
// Block = 128 threads = 2 waves; both waves own the SAME 128x128 output tile,
// wave kh handles K-half [kh*2048, kh*2048+2048). mi=ni=4, 32x32x16 MFMA,
// acc 256 VGPR at 1 wave/SIMD -> zero LDS fragment duplication: per block-step
// 32KB LDS reads vs 1536 SIMD-cy of MFMA => MFMA-bound (round-2-calibrated
// model: LDS read BW 256B/cy/CU, gload_lds writes don't contend reads).
// W is consumed as RAW f32 (scatter output) — hi/lo split happens in UNPACK,
// eliminating the packW pass (same 4B/elem staging either way).
// A tile LDS: [128 rows][2 kh][16k f32] = 128B/row (16KB); B: [128 cols][2 kh]
// [2 plane][16k bf16] = 128B/row (16KB). 16B chunk c of row r at physical
// c ^ (r&7): sources pre-swizzled, gload_lds dest linear (rule 21).
#define WAIT_LGKM0 do { asm volatile("s_waitcnt lgkmcnt(0)" ::: "memory"); \
                        __builtin_amdgcn_sched_barrier(0); } while (0)
#define WAIT_VM(N)  asm volatile("s_waitcnt vmcnt(" #N ")" ::: "memory")
#define BAR         __builtin_amdgcn_s_barrier()

#define STAGE(BS) do { \
  _Pragma("unroll") for (int j = 0; j < 8; ++j) \
    __builtin_amdgcn_global_load_lds((gptr_t)(aPtr + j * 262144), \
        (lptr_t)(lds + (BS) * 32768 + j * 2048 + kh * 1024), 16, 0, 0); \
  _Pragma("unroll") for (int j = 0; j < 8; ++j) \
    __builtin_amdgcn_global_load_lds((gptr_t)(bPtr + j * 131072), \
        (lptr_t)(lds + (BS) * 32768 + 16384 + j * 2048 + kh * 1024), 16, 0, 0); \
  aPtr += 64; bPtr += 32; \
} while (0)

#define READS(S, BO) do { \
  _Pragma("unroll") for (int mi = 0; mi < 4; ++mi) { \
    Ar##S[mi][0] = *(const uint4*)(lds + (BO) + aOff[mi][0]); \
    Ar##S[mi][1] = *(const uint4*)(lds + (BO) + aOff[mi][1]); } \
  _Pragma("unroll") for (int ni = 0; ni < 4; ++ni) { \
    Bh##S[ni] = *(const bf16x8*)(lds + (BO) + 16384 + bOff[ni][0]); \
    Bl##S[ni] = *(const bf16x8*)(lds + (BO) + 16384 + bOff[ni][1]); } \
} while (0)

#define UNPACK(S) do { \
  _Pragma("unroll") for (int mi = 0; mi < 4; ++mi) { \
    uint4 q0 = Ar##S[mi][0], q1 = Ar##S[mi][1]; \
    u32x4 h, l; \
    uint32_t th, tl; \
    split2(q0.x, q0.y, th, tl); h[0] = th; l[0] = tl; \
    split2(q0.z, q0.w, th, tl); h[1] = th; l[1] = tl; \
    split2(q1.x, q1.y, th, tl); h[2] = th; l[2] = tl; \
    split2(q1.z, q1.w, th, tl); h[3] = th; l[3] = tl; \
    Ah##S[mi] = __builtin_bit_cast(bf16x8, h); \
    Al##S[mi] = __builtin_bit_cast(bf16x8, l); } \
} while (0)

#define MFMAS(S) do { \
  _Pragma("unroll") for (int mi = 0; mi < 4; ++mi) \
  _Pragma("unroll") for (int ni = 0; ni < 4; ++ni) \
    acc[mi][ni] = __builtin_amdgcn_mfma_f32_32x32x16_bf16(Ah##S[mi], Bh##S[ni], acc[mi][ni], 0, 0, 0); \
  _Pragma("unroll") for (int mi = 0; mi < 4; ++mi) \
  _Pragma("unroll") for (int ni = 0; ni < 4; ++ni) \
    acc[mi][ni] = __builtin_amdgcn_mfma_f32_32x32x16_bf16(Ah##S[mi], Bl##S[ni], acc[mi][ni], 0, 0, 0); \
  _Pragma("unroll") for (int mi = 0; mi < 4; ++mi) \
  _Pragma("unroll") for (int ni = 0; ni < 4; ++ni) \
    acc[mi][ni] = __builtin_amdgcn_mfma_f32_32x32x16_bf16(Al##S[mi], Bh##S[ni], acc[mi][ni], 0, 0, 0); \
} while (0)

#define STEP(C, N, t) do { \
  if ((t) < 126) { STAGE((t) & 1); WAIT_VM(16); } \
  else if ((t) == 126) { WAIT_VM(0); } \
  if ((t) < 127) { BAR; READS(N, (((t) + 1) & 1) * 32768); } \
  __builtin_amdgcn_s_setprio(1); MFMAS(C); __builtin_amdgcn_s_setprio(0); \
  if ((t) < 127) { WAIT_LGKM0; UNPACK(N); BAR; } \
} while (0)

__global__ __launch_bounds__(128, 1) void gemm_kernel(
    const uint32_t* __restrict__ Wp, const uint16_t* __restrict__ Xh,
    const uint16_t* __restrict__ Xl, const float* __restrict__ bias,
    float* __restrict__ out) {
  __shared__ __align__(16) uint8_t lds[67584];  // 2x32KB dbuf; reused as C[128][132] f32
  const unsigned tid = threadIdx.x, lane = tid & 63, kh = tid >> 6;
  const unsigned ln31 = lane & 31, l5 = lane >> 5;

  // bijective XCD swizzle (512 blocks): per XCD all 32 bm x 2 bn (X panels L2-fit)
  unsigned newid = (blockIdx.x & 7) * 64 + (blockIdx.x >> 3);
  const unsigned bm = newid & 31, bn = newid >> 5;

  // staging sources (pre-swizzled global addresses; LDS dest linear).
  // sc bits for A: [2]=K-half, [1:0]=16B sub-chunk; for B: [2]=K-half,
  // [1]=plane (hi/lo buffer), [0]=16B sub-chunk.
  const unsigned tg = tid >> 3;                   // 0..15
  const unsigned sc = (tid & 7) ^ (tg & 7);       // swizzled chunk for this lane
  const uint8_t* aPtr = (const uint8_t*)Wp + (size_t)(bm * 128 + tg) * (INF * 4)
                        + (sc >> 2) * (2048 * 4) + (sc & 3) * 16;
  const uint16_t* xb = ((sc >> 1) & 1) ? Xl : Xh;
  const uint8_t* bPtr = (const uint8_t*)xb + (size_t)(bn * 128 + tg) * (INF * 2)
                        + (sc >> 2) * (2048 * 2) + (sc & 1) * 16;

  // fragment LDS byte offsets (step-invariant)
  unsigned aOff[4][2], bOff[4][2];
#pragma unroll
  for (int mi = 0; mi < 4; ++mi) {
    unsigned row = mi * 32 + ln31, x = row & 7, c0 = kh * 4 + l5 * 2;
    aOff[mi][0] = row * 128 + ((c0 ^ x) << 4);
    aOff[mi][1] = row * 128 + (((c0 + 1) ^ x) << 4);
  }
#pragma unroll
  for (int ni = 0; ni < 4; ++ni) {
    unsigned col = ni * 32 + ln31, x = col & 7;
    bOff[ni][0] = col * 128 + (((kh * 4 + 0 + l5) ^ x) << 4);  // hi plane
    bOff[ni][1] = col * 128 + (((kh * 4 + 2 + l5) ^ x) << 4);  // lo plane
  }

  f32x16 acc[4][4];
#pragma unroll
  for (int mi = 0; mi < 4; ++mi)
#pragma unroll
    for (int ni = 0; ni < 4; ++ni) acc[mi][ni] = (f32x16)(0.0f);

  uint4 Ar0[4][2], Ar1[4][2];
  bf16x8 Ah0[4], Al0[4], Bh0[4], Bl0[4];
  bf16x8 Ah1[4], Al1[4], Bh1[4], Bl1[4];

  // prologue: tiles 0,1 in flight; land tile 0; load+unpack step-0 fragments
  STAGE(0);
  STAGE(1);
  WAIT_VM(16);
  BAR;
  READS(0, 0u);
  WAIT_LGKM0;
  UNPACK(0);

  for (unsigned t = 0; t < T_STEPS; t += 2) {
    STEP(0, 1, t);
    STEP(1, 0, t + 1);
  }

  // ---- combine the two K-halves through LDS (padded C[128][132] f32) ----
  float* C = (float*)lds;
  BAR;  // all LDS reads of the K-loop are done (lgkm drained at t=126)
  if (kh == 0) {
#pragma unroll
    for (int mi = 0; mi < 4; ++mi)
#pragma unroll
      for (int ni = 0; ni < 4; ++ni)
#pragma unroll
        for (int r = 0; r < 16; ++r) {
          unsigned row = mi * 32 + (r & 3) + 8 * (r >> 2) + 4 * l5;
          C[row * 132 + ni * 32 + ln31] = acc[mi][ni][r];
        }
  }
  BAR;
  if (kh == 1) {
#pragma unroll
    for (int mi = 0; mi < 4; ++mi)
#pragma unroll
      for (int ni = 0; ni < 4; ++ni)
#pragma unroll
        for (int r = 0; r < 16; ++r) {
          unsigned row = mi * 32 + (r & 3) + 8 * (r >> 2) + 4 * l5;
          C[row * 132 + ni * 32 + ln31] += acc[mi][ni][r];
        }
  }
  BAR;
  // transposed, coalesced float4 write-out with bias (both waves)
#pragma unroll 4
  for (unsigned it = 0; it < 32; ++it) {
    unsigned idx = it * 128 + tid;
    unsigned row = idx >> 5, c4 = idx & 31;
    f32x4 v = *(const f32x4*)(C + row * 132 + c4 * 4);
    float b = bias[bm * 128 + row];
    v[0] += b; v[1] += b; v[2] += b; v[3] += b;
    *(f32x4*)(out + (size_t)(bm * 128 + row) * NBAT + bn * 128 + c4 * 4) = v;
  }
}

extern "C" void kernel_launch(void* const* d_in, const int* in_sizes, int n_in,
                              void* d_out, int out_size, void* d_ws, size_t ws_size,
                              hipStream_t stream) {
  const float* inp    = (const float*)d_in[0];
  const float* values = (const float*)d_in[1];
  const float* bias   = (const float*)d_in[2];
  const int*   rows   = (const int*)d_in[3];
  const int*   cols   = (const int*)d_in[4];
  const int nnz = in_sizes[1];
  float* out = (float*)d_out;

  uint8_t* ws = (uint8_t*)d_ws;
  float*    W  = (float*)ws;                      // 64 MB raw f32 (GEMM reads directly)
  uint16_t* Xh = (uint16_t*)(ws + (64u << 20));   // 16 MB
  uint16_t* Xl = (uint16_t*)(ws + (80u << 20));   // 16 MB

  zero_packX_kernel<<<16384 + 8192, 256, 0, stream>>>((uint4*)W, inp, Xh, Xl);
  scatter_kernel<<<(nnz + 255) / 256, 256, 0, stream>>>(values, rows, cols, W, nnz);
  gemm_kernel<<<512, 128, 0, stream>>>((const uint32_t*)W, Xh, Xl, bias, out);
}

// Round 7
// 1138.608 us; speedup vs baseline: 1.2204x; 1.2204x over previous
//
#include <hip/hip_runtime.h>
#include <stdint.h>

#define OUTF 4096
#define INF  4096
#define NBAT 2048

typedef __attribute__((ext_vector_type(8))) short bf16x8;
typedef __attribute__((ext_vector_type(16))) float f32x16;
typedef __attribute__((ext_vector_type(4))) float f32x4;
typedef const __attribute__((address_space(1))) uint8_t* gptr_t;
typedef __attribute__((address_space(3))) uint8_t* lptr_t;

__device__ __forceinline__ uint32_t f2bf(float f) {
  uint32_t u = __builtin_bit_cast(uint32_t, f);
  return (u + 0x7FFFu + ((u >> 16) & 1u)) >> 16;
}

// pack two f32 into one hi-bf16-pair word and one lo-bf16-pair word
__device__ __forceinline__ void packpair(float f0, float f1, uint32_t& hw, uint32_t& lw) {
  uint32_t h0 = f2bf(f0), h1 = f2bf(f1);
  float r0 = f0 - __builtin_bit_cast(float, h0 << 16);
  float r1 = f1 - __builtin_bit_cast(float, h1 << 16);
  hw = h0 | (h1 << 16);
  lw = (__builtin_bit_cast(uint32_t, r0) >> 16) |
       (__builtin_bit_cast(uint32_t, r1) & 0xFFFF0000u);
}

// ---- zero W (64MB) + transpose/split X -> Xp[n][k8-group][hi 16B][lo 16B] ----
__global__ void zero_packX_kernel(uint4* __restrict__ W, const float* __restrict__ X,
                                  uint8_t* __restrict__ Xp) {
  unsigned bid = blockIdx.x;
  if (bid < 16384) {
    W[(size_t)bid * 256 + threadIdx.x] = make_uint4(0u, 0u, 0u, 0u);
    return;
  }
  bid -= 16384;
  __shared__ float t[32][33];
  int n0 = (bid & 63) * 32, k0 = (bid >> 6) * 32;
  int tx = threadIdx.x & 31, ty = threadIdx.x >> 5;  // 32 x 8
#pragma unroll
  for (int j = 0; j < 4; ++j)
    t[ty + j * 8][tx] = X[(size_t)(k0 + ty + j * 8) * NBAT + n0 + tx];
  __syncthreads();
  if (threadIdx.x < 128) {
    int n = threadIdx.x >> 2, kg = threadIdx.x & 3;   // 32 n x 4 k-groups
    uint32_t hw[4], lw[4];
#pragma unroll
    for (int w = 0; w < 4; ++w) {
      uint32_t h, l;
      packpair(t[kg * 8 + 2 * w][n], t[kg * 8 + 2 * w + 1][n], h, l);
      hw[w] = h; lw[w] = l;
    }
    uint8_t* dst = Xp + (size_t)(n0 + n) * 16384 + (size_t)k0 * 4 + kg * 32;
    *(uint4*)dst        = make_uint4(hw[0], hw[1], hw[2], hw[3]);
    *(uint4*)(dst + 16) = make_uint4(lw[0], lw[1], lw[2], lw[3]);
  }
}

// ---- COO scatter-add (sums duplicates, matches .at[].add) ----
__global__ void scatter_kernel(const float* __restrict__ vals,
                               const int* __restrict__ rows,
                               const int* __restrict__ cols,
                               float* __restrict__ W, int nnz) {
  int i = blockIdx.x * blockDim.x + threadIdx.x;
  if (i < nnz) atomicAdd(&W[(size_t)rows[i] * INF + cols[i]], vals[i]);
}

// ---- pack W in place: per 8-elem group (32B): [hi bf16 x8][lo bf16 x8] ----
// Thread owns one 32B group -> in-place safe.
__global__ void packW_kernel(uint32_t* __restrict__ W) {
  size_t g = (size_t)blockIdx.x * 256 + threadIdx.x;
  uint4* p = (uint4*)(W + g * 8);
  uint4 a = p[0], b = p[1];
  uint32_t h0, l0, h1, l1, h2, l2, h3, l3;
  packpair(__builtin_bit_cast(float, a.x), __builtin_bit_cast(float, a.y), h0, l0);
  packpair(__builtin_bit_cast(float, a.z), __builtin_bit_cast(float, a.w), h1, l1);
  packpair(__builtin_bit_cast(float, b.x), __builtin_bit_cast(float, b.y), h2, l2);
  packpair(__builtin_bit_cast(float, b.z), __builtin_bit_cast(float, b.w), h3, l3);
  p[0] = make_uint4(h0, h1, h2, h3);
  p[1] = make_uint4(l0, l1, l2, l3);
}

// ---- split-K split-bf16 GEMM, frag-major LDS (conflict-free, zero-unpack) ----
// Block = 128 threads = 2 waves; both own the SAME 128x128 tile; wave kh does
// the even(kh=0)/odd(kh=1) K16 chunks of each K32 tile. mi=ni=4, 32x32x16 MFMA.
// acc 256 regs (AGPR side); arch-VGPR side: frags 2x64 + staging ~35 << 256.
// LDS per set (32KB): A = 16 frag-blocks [mi(4)][plane(2)][kh(2)] x 1KB
// (lane-major, ds_read_b128 reads a contiguous 1KB -> conflict-free);
// B mirror at +16KB. Staged by 16 global_load_lds (dest linear 2KB/instr).
#define WAIT_VM(N) asm volatile("s_waitcnt vmcnt(" #N ")" ::: "memory")
#define LGKM0 do { asm volatile("s_waitcnt lgkmcnt(0)" ::: "memory"); \
                   __builtin_amdgcn_sched_barrier(0); } while (0)
#define BAR __builtin_amdgcn_s_barrier()

// global source for LDS block blk (=[x][plane][kh]): x*32rows*16KB + kh*64 + plane*16
#define SRCOFF(blk) (((blk) >> 2) * 524288u + ((blk) & 1) * 64u + (((blk) >> 1) & 1) * 16u)

#define STAGE(BS) do { \
  _Pragma("unroll") for (int j = 0; j < 8; ++j) { \
    unsigned blk = 2 * j + wid; \
    __builtin_amdgcn_global_load_lds((gptr_t)(aB + SRCOFF(blk)), \
        (lptr_t)(lds + (BS) * 32768 + j * 2048 + wid * 1024), 16, 0, 0); \
    __builtin_amdgcn_global_load_lds((gptr_t)(bB + SRCOFF(blk)), \
        (lptr_t)(lds + (BS) * 32768 + 16384 + j * 2048 + wid * 1024), 16, 0, 0); } \
  aB += 128; bB += 128; \
} while (0)

#define READF(S, BS) do { \
  _Pragma("unroll") for (int mi = 0; mi < 4; ++mi) { \
    Ah##S[mi] = *(const bf16x8*)(lds + vds + ((BS) * 32768 + mi * 4096)); \
    Al##S[mi] = *(const bf16x8*)(lds + vds + ((BS) * 32768 + mi * 4096 + 2048)); } \
  _Pragma("unroll") for (int ni = 0; ni < 4; ++ni) { \
    Bh##S[ni] = *(const bf16x8*)(lds + vds + ((BS) * 32768 + 16384 + ni * 4096)); \
    Bl##S[ni] = *(const bf16x8*)(lds + vds + ((BS) * 32768 + 16384 + ni * 4096 + 2048)); } \
} while (0)

#define MFMAS(S) do { \
  _Pragma("unroll") for (int mi = 0; mi < 4; ++mi) \
  _Pragma("unroll") for (int ni = 0; ni < 4; ++ni) \
    acc[mi][ni] = __builtin_amdgcn_mfma_f32_32x32x16_bf16(Ah##S[mi], Bh##S[ni], acc[mi][ni], 0, 0, 0); \
  _Pragma("unroll") for (int mi = 0; mi < 4; ++mi) \
  _Pragma("unroll") for (int ni = 0; ni < 4; ++ni) \
    acc[mi][ni] = __builtin_amdgcn_mfma_f32_32x32x16_bf16(Ah##S[mi], Bl##S[ni], acc[mi][ni], 0, 0, 0); \
  _Pragma("unroll") for (int mi = 0; mi < 4; ++mi) \
  _Pragma("unroll") for (int ni = 0; ni < 4; ++ni) \
    acc[mi][ni] = __builtin_amdgcn_mfma_f32_32x32x16_bf16(Al##S[mi], Bh##S[ni], acc[mi][ni], 0, 0, 0); \
} while (0)

#define STEP(C, N, t) do { \
  if ((t) < 126) { STAGE((t) & 1); WAIT_VM(16); } \
  else if ((t) == 126) { WAIT_VM(0); } \
  if ((t) < 127) { BAR; READF(N, ((t) + 1) & 1); } \
  __builtin_amdgcn_s_setprio(1); MFMAS(C); __builtin_amdgcn_s_setprio(0); \
  if ((t) < 127) { LGKM0; BAR; } \
} while (0)

__global__ __launch_bounds__(128, 1) void gemm_kernel(
    const uint8_t* __restrict__ Wp, const uint8_t* __restrict__ Xp,
    const float* __restrict__ bias, float* __restrict__ out) {
  __shared__ __align__(16) uint8_t lds[67584];  // 2x32KB dbuf; reused as C[128][132]
  const unsigned tid = threadIdx.x, lane = tid & 63, wid = tid >> 6, kh = wid;
  const unsigned ln31 = lane & 31, l5 = lane >> 5;

  // bijective XCD swizzle (512 blocks): each XCD gets 2 bn panels (4MB X, L2-fit)
  unsigned newid = (blockIdx.x & 7) * 64 + (blockIdx.x >> 3);
  const unsigned bm = newid & 31, bn = newid >> 5;

  // staging bases (per-thread); per-instr constant adds via SRCOFF
  const uint8_t* aB = Wp + (size_t)bm * 2097152 + ln31 * 16384 + l5 * 32;
  const uint8_t* bB = Xp + (size_t)bn * 2097152 + ln31 * 16384 + l5 * 32;
  // single ds vaddr; all 32 frag reads use compile-time offset immediates
  const unsigned vds = kh * 1024 + lane * 16;

  f32x16 acc[4][4];
#pragma unroll
  for (int mi = 0; mi < 4; ++mi)
#pragma unroll
    for (int ni = 0; ni < 4; ++ni) acc[mi][ni] = (f32x16)(0.0f);

  bf16x8 Ah0[4], Al0[4], Bh0[4], Bl0[4];
  bf16x8 Ah1[4], Al1[4], Bh1[4], Bl1[4];

  // prologue: tiles 0,1 in flight; land 0; read F0; publish before overwrite
  STAGE(0);
  STAGE(1);
  WAIT_VM(16);
  BAR;
  READF(0, 0);
  LGKM0;
  BAR;

  for (unsigned t = 0; t < 128; t += 2) {
    STEP(0, 1, t);
    STEP(1, 0, t + 1);
  }

  // ---- combine K-halves through LDS (padded C[128][132] f32) ----
  float* C = (float*)lds;
  BAR;
  if (kh == 0) {
#pragma unroll
    for (int mi = 0; mi < 4; ++mi)
#pragma unroll
      for (int ni = 0; ni < 4; ++ni)
#pragma unroll
        for (int r = 0; r < 16; ++r) {
          unsigned row = mi * 32 + (r & 3) + 8 * (r >> 2) + 4 * l5;
          C[row * 132 + ni * 32 + ln31] = acc[mi][ni][r];
        }
  }
  BAR;
  if (kh == 1) {
#pragma unroll
    for (int mi = 0; mi < 4; ++mi)
#pragma unroll
      for (int ni = 0; ni < 4; ++ni)
#pragma unroll
        for (int r = 0; r < 16; ++r) {
          unsigned row = mi * 32 + (r & 3) + 8 * (r >> 2) + 4 * l5;
          C[row * 132 + ni * 32 + ln31] += acc[mi][ni][r];
        }
  }
  BAR;
  // coalesced float4 write-out with bias (both waves)
#pragma unroll 4
  for (unsigned it = 0; it < 32; ++it) {
    unsigned idx = it * 128 + tid;
    unsigned row = idx >> 5, c4 = idx & 31;
    f32x4 v = *(const f32x4*)(C + row * 132 + c4 * 4);
    float b = bias[bm * 128 + row];
    v[0] += b; v[1] += b; v[2] += b; v[3] += b;
    *(f32x4*)(out + (size_t)(bm * 128 + row) * NBAT + bn * 128 + c4 * 4) = v;
  }
}

extern "C" void kernel_launch(void* const* d_in, const int* in_sizes, int n_in,
                              void* d_out, int out_size, void* d_ws, size_t ws_size,
                              hipStream_t stream) {
  const float* inp    = (const float*)d_in[0];
  const float* values = (const float*)d_in[1];
  const float* bias   = (const float*)d_in[2];
  const int*   rows   = (const int*)d_in[3];
  const int*   cols   = (const int*)d_in[4];
  const int nnz = in_sizes[1];
  float* out = (float*)d_out;

  uint8_t* ws = (uint8_t*)d_ws;
  float*   W  = (float*)ws;                 // 64 MB: raw f32 -> packed planes in place
  uint8_t* Xp = ws + (64u << 20);           // 32 MB: plane-grouped X^T

  zero_packX_kernel<<<16384 + 8192, 256, 0, stream>>>((uint4*)W, inp, Xp);
  scatter_kernel<<<(nnz + 255) / 256, 256, 0, stream>>>(values, rows, cols, W, nnz);
  packW_kernel<<<8192, 256, 0, stream>>>((uint32_t*)W);
  gemm_kernel<<<512, 128, 0, stream>>>((const uint8_t*)W, Xp, bias, out);
}

// Round 8
// 1129.057 us; speedup vs baseline: 1.2307x; 1.0085x over previous
//
#include <hip/hip_runtime.h>
#include <stdint.h>

#define OUTF 4096
#define INF  4096
#define NBAT 2048

typedef __attribute__((ext_vector_type(8))) short bf16x8;
typedef __attribute__((ext_vector_type(16))) float f32x16;
typedef __attribute__((ext_vector_type(4))) float f32x4;
typedef const __attribute__((address_space(1))) uint8_t* gptr_t;
typedef __attribute__((address_space(3))) uint8_t* lptr_t;

__device__ __forceinline__ uint32_t f2bf(float f) {
  uint32_t u = __builtin_bit_cast(uint32_t, f);
  return (u + 0x7FFFu + ((u >> 16) & 1u)) >> 16;
}

// pack two f32 into one hi-bf16-pair word and one lo-bf16-pair word
__device__ __forceinline__ void packpair(float f0, float f1, uint32_t& hw, uint32_t& lw) {
  uint32_t h0 = f2bf(f0), h1 = f2bf(f1);
  float r0 = f0 - __builtin_bit_cast(float, h0 << 16);
  float r1 = f1 - __builtin_bit_cast(float, h1 << 16);
  hw = h0 | (h1 << 16);
  lw = (__builtin_bit_cast(uint32_t, r0) >> 16) |
       (__builtin_bit_cast(uint32_t, r1) & 0xFFFF0000u);
}

// ---- zero W (64MB) + transpose/split X -> Xp[n][k8-group][hi 16B][lo 16B] ----
__global__ void zero_packX_kernel(uint4* __restrict__ W, const float* __restrict__ X,
                                  uint8_t* __restrict__ Xp) {
  unsigned bid = blockIdx.x;
  if (bid < 16384) {
    W[(size_t)bid * 256 + threadIdx.x] = make_uint4(0u, 0u, 0u, 0u);
    return;
  }
  bid -= 16384;
  __shared__ float t[32][33];
  int n0 = (bid & 63) * 32, k0 = (bid >> 6) * 32;
  int tx = threadIdx.x & 31, ty = threadIdx.x >> 5;  // 32 x 8
#pragma unroll
  for (int j = 0; j < 4; ++j)
    t[ty + j * 8][tx] = X[(size_t)(k0 + ty + j * 8) * NBAT + n0 + tx];
  __syncthreads();
  if (threadIdx.x < 128) {
    int n = threadIdx.x >> 2, kg = threadIdx.x & 3;   // 32 n x 4 k-groups
    uint32_t hw[4], lw[4];
#pragma unroll
    for (int w = 0; w < 4; ++w) {
      uint32_t h, l;
      packpair(t[kg * 8 + 2 * w][n], t[kg * 8 + 2 * w + 1][n], h, l);
      hw[w] = h; lw[w] = l;
    }
    uint8_t* dst = Xp + (size_t)(n0 + n) * 16384 + (size_t)k0 * 4 + kg * 32;
    *(uint4*)dst        = make_uint4(hw[0], hw[1], hw[2], hw[3]);
    *(uint4*)(dst + 16) = make_uint4(lw[0], lw[1], lw[2], lw[3]);
  }
}

// ---- COO scatter-add (sums duplicates, matches .at[].add) ----
__global__ void scatter_kernel(const float* __restrict__ vals,
                               const int* __restrict__ rows,
                               const int* __restrict__ cols,
                               float* __restrict__ W, int nnz) {
  int i = blockIdx.x * blockDim.x + threadIdx.x;
  if (i < nnz) atomicAdd(&W[(size_t)rows[i] * INF + cols[i]], vals[i]);
}

// ---- pack W in place: per 8-elem group (32B): [hi bf16 x8][lo bf16 x8] ----
__global__ void packW_kernel(uint32_t* __restrict__ W) {
  size_t g = (size_t)blockIdx.x * 256 + threadIdx.x;
  uint4* p = (uint4*)(W + g * 8);
  uint4 a = p[0], b = p[1];
  uint32_t h0, l0, h1, l1, h2, l2, h3, l3;
  packpair(__builtin_bit_cast(float, a.x), __builtin_bit_cast(float, a.y), h0, l0);
  packpair(__builtin_bit_cast(float, a.z), __builtin_bit_cast(float, a.w), h1, l1);
  packpair(__builtin_bit_cast(float, b.x), __builtin_bit_cast(float, b.y), h2, l2);
  packpair(__builtin_bit_cast(float, b.z), __builtin_bit_cast(float, b.w), h3, l3);
  p[0] = make_uint4(h0, h1, h2, h3);
  p[1] = make_uint4(l0, l1, l2, l3);
}

// ---- split-K split-bf16 GEMM, frag-major LDS, AGPR-pinned accumulator --------
// Round-7 structure (verified correct, 0 bank conflicts) with ONE change:
// MFMA via inline asm with "+a" accumulator constraint. Round 6/7 spilled
// (WRITE_SIZE 1.27-2GB, VGPR_Count pinned at 256): hipcc kept the 256-reg acc
// in VGPR-form on gfx950's unified file, overflowing the 256 arch-VGPR cap.
// "+a" pins acc into the (otherwise idle) 256-AGPR file; arch side = frags
// (128) + staging (~25) < 256 -> no spill.
#define WAIT_VM(N) asm volatile("s_waitcnt vmcnt(" #N ")" ::: "memory")
#define LGKM0 do { asm volatile("s_waitcnt lgkmcnt(0)" ::: "memory"); \
                   __builtin_amdgcn_sched_barrier(0); } while (0)
#define BAR __builtin_amdgcn_s_barrier()

// one 32x32x16 bf16 MFMA, accumulator pinned in AGPRs
#define MFMA1(D, A, B) \
  asm("v_mfma_f32_32x32x16_bf16 %0, %1, %2, %0" : "+a"(D) : "v"(A), "v"(B))

// global source for LDS block blk (=[x][plane][kh]): x*32rows*16KB + kh*64 + plane*16
#define SRCOFF(blk) (((blk) >> 2) * 524288u + ((blk) & 1) * 64u + (((blk) >> 1) & 1) * 16u)

#define STAGE(BS) do { \
  _Pragma("unroll") for (int j = 0; j < 8; ++j) { \
    unsigned blk = 2 * j + wid; \
    __builtin_amdgcn_global_load_lds((gptr_t)(aB + SRCOFF(blk)), \
        (lptr_t)(lds + (BS) * 32768 + j * 2048 + wid * 1024), 16, 0, 0); \
    __builtin_amdgcn_global_load_lds((gptr_t)(bB + SRCOFF(blk)), \
        (lptr_t)(lds + (BS) * 32768 + 16384 + j * 2048 + wid * 1024), 16, 0, 0); } \
  aB += 128; bB += 128; \
} while (0)

#define READF(S, BS) do { \
  _Pragma("unroll") for (int mi = 0; mi < 4; ++mi) { \
    Ah##S[mi] = *(const bf16x8*)(lds + vds + ((BS) * 32768 + mi * 4096)); \
    Al##S[mi] = *(const bf16x8*)(lds + vds + ((BS) * 32768 + mi * 4096 + 2048)); } \
  _Pragma("unroll") for (int ni = 0; ni < 4; ++ni) { \
    Bh##S[ni] = *(const bf16x8*)(lds + vds + ((BS) * 32768 + 16384 + ni * 4096)); \
    Bl##S[ni] = *(const bf16x8*)(lds + vds + ((BS) * 32768 + 16384 + ni * 4096 + 2048)); } \
} while (0)

#define MFMAS(S) do { \
  _Pragma("unroll") for (int mi = 0; mi < 4; ++mi) \
  _Pragma("unroll") for (int ni = 0; ni < 4; ++ni) \
    MFMA1(acc[mi][ni], Ah##S[mi], Bh##S[ni]); \
  _Pragma("unroll") for (int mi = 0; mi < 4; ++mi) \
  _Pragma("unroll") for (int ni = 0; ni < 4; ++ni) \
    MFMA1(acc[mi][ni], Ah##S[mi], Bl##S[ni]); \
  _Pragma("unroll") for (int mi = 0; mi < 4; ++mi) \
  _Pragma("unroll") for (int ni = 0; ni < 4; ++ni) \
    MFMA1(acc[mi][ni], Al##S[mi], Bh##S[ni]); \
} while (0)

#define STEP(C, N, t) do { \
  if ((t) < 126) { STAGE((t) & 1); WAIT_VM(16); } \
  else if ((t) == 126) { WAIT_VM(0); } \
  if ((t) < 127) { BAR; READF(N, ((t) + 1) & 1); } \
  __builtin_amdgcn_s_setprio(1); MFMAS(C); __builtin_amdgcn_s_setprio(0); \
  if ((t) < 127) { LGKM0; BAR; } \
} while (0)

__global__ __launch_bounds__(128, 1) void gemm_kernel(
    const uint8_t* __restrict__ Wp, const uint8_t* __restrict__ Xp,
    const float* __restrict__ bias, float* __restrict__ out) {
  __shared__ __align__(16) uint8_t lds[67584];  // 2x32KB dbuf; reused as C[128][132]
  const unsigned tid = threadIdx.x, lane = tid & 63, wid = tid >> 6, kh = wid;
  const unsigned ln31 = lane & 31, l5 = lane >> 5;

  // bijective XCD swizzle (512 blocks): each XCD gets 2 bn panels (4MB X, L2-fit)
  unsigned newid = (blockIdx.x & 7) * 64 + (blockIdx.x >> 3);
  const unsigned bm = newid & 31, bn = newid >> 5;

  // staging bases (per-thread); per-instr constant adds via SRCOFF
  const uint8_t* aB = Wp + (size_t)bm * 2097152 + ln31 * 16384 + l5 * 32;
  const uint8_t* bB = Xp + (size_t)bn * 2097152 + ln31 * 16384 + l5 * 32;
  // single ds vaddr; all 32 frag reads use compile-time offset immediates
  const unsigned vds = kh * 1024 + lane * 16;

  f32x16 acc[4][4];
#pragma unroll
  for (int mi = 0; mi < 4; ++mi)
#pragma unroll
    for (int ni = 0; ni < 4; ++ni) acc[mi][ni] = (f32x16)(0.0f);

  bf16x8 Ah0[4], Al0[4], Bh0[4], Bl0[4];
  bf16x8 Ah1[4], Al1[4], Bh1[4], Bl1[4];

  // prologue: tiles 0,1 in flight; land 0; read F0; publish before overwrite
  STAGE(0);
  STAGE(1);
  WAIT_VM(16);
  BAR;
  READF(0, 0);
  LGKM0;
  BAR;

  for (unsigned t = 0; t < 128; t += 2) {
    STEP(0, 1, t);
    STEP(1, 0, t + 1);
  }

  // ---- combine K-halves through LDS (padded C[128][132] f32) ----
  float* C = (float*)lds;
  BAR;
  if (kh == 0) {
#pragma unroll
    for (int mi = 0; mi < 4; ++mi)
#pragma unroll
      for (int ni = 0; ni < 4; ++ni)
#pragma unroll
        for (int r = 0; r < 16; ++r) {
          unsigned row = mi * 32 + (r & 3) + 8 * (r >> 2) + 4 * l5;
          C[row * 132 + ni * 32 + ln31] = acc[mi][ni][r];
        }
  }
  BAR;
  if (kh == 1) {
#pragma unroll
    for (int mi = 0; mi < 4; ++mi)
#pragma unroll
      for (int ni = 0; ni < 4; ++ni)
#pragma unroll
        for (int r = 0; r < 16; ++r) {
          unsigned row = mi * 32 + (r & 3) + 8 * (r >> 2) + 4 * l5;
          C[row * 132 + ni * 32 + ln31] += acc[mi][ni][r];
        }
  }
  BAR;
  // coalesced float4 write-out with bias (both waves)
#pragma unroll 4
  for (unsigned it = 0; it < 32; ++it) {
    unsigned idx = it * 128 + tid;
    unsigned row = idx >> 5, c4 = idx & 31;
    f32x4 v = *(const f32x4*)(C + row * 132 + c4 * 4);
    float b = bias[bm * 128 + row];
    v[0] += b; v[1] += b; v[2] += b; v[3] += b;
    *(f32x4*)(out + (size_t)(bm * 128 + row) * NBAT + bn * 128 + c4 * 4) = v;
  }
}

extern "C" void kernel_launch(void* const* d_in, const int* in_sizes, int n_in,
                              void* d_out, int out_size, void* d_ws, size_t ws_size,
                              hipStream_t stream) {
  const float* inp    = (const float*)d_in[0];
  const float* values = (const float*)d_in[1];
  const float* bias   = (const float*)d_in[2];
  const int*   rows   = (const int*)d_in[3];
  const int*   cols   = (const int*)d_in[4];
  const int nnz = in_sizes[1];
  float* out = (float*)d_out;

  uint8_t* ws = (uint8_t*)d_ws;
  float*   W  = (float*)ws;                 // 64 MB: raw f32 -> packed planes in place
  uint8_t* Xp = ws + (64u << 20);           // 32 MB: plane-grouped X^T

  zero_packX_kernel<<<16384 + 8192, 256, 0, stream>>>((uint4*)W, inp, Xp);
  scatter_kernel<<<(nnz + 255) / 256, 256, 0, stream>>>(values, rows, cols, W, nnz);
  packW_kernel<<<8192, 256, 0, stream>>>((uint32_t*)W);
  gemm_kernel<<<512, 128, 0, stream>>>((const uint8_t*)W, Xp, bias, out);
}

// Round 9
// 390.445 us; speedup vs baseline: 3.5590x; 2.8917x over previous
//
#include <hip/hip_runtime.h>
#include <stdint.h>

#define OUTF 4096
#define INF  4096
#define NBAT 2048
#define BM 128
#define BN 128

typedef __attribute__((ext_vector_type(8))) short bf16x8;
typedef __attribute__((ext_vector_type(4))) float f32x4;
typedef __attribute__((ext_vector_type(4))) unsigned int u32x4;
typedef const __attribute__((address_space(1))) uint8_t* gptr_t;
typedef __attribute__((address_space(3))) uint8_t* lptr_t;

__device__ __forceinline__ uint32_t f2bf(float f) {
  uint32_t u = __builtin_bit_cast(uint32_t, f);
  return (u + 0x7FFFu + ((u >> 16) & 1u)) >> 16;
}

// split two raw f32 into one packed hi-pair word and one lo-pair word
// (element j in low half of word pair; matches round-2 packed layout).
__device__ __forceinline__ void split2(uint32_t u0, uint32_t u1,
                                       uint32_t& h, uint32_t& l) {
  uint32_t h0 = (u0 + 0x7FFFu + ((u0 >> 16) & 1u)) >> 16;
  uint32_t h1 = (u1 + 0x7FFFu + ((u1 >> 16) & 1u)) >> 16;
  float r0 = __builtin_bit_cast(float, u0) - __builtin_bit_cast(float, h0 << 16);
  float r1 = __builtin_bit_cast(float, u1) - __builtin_bit_cast(float, h1 << 16);
  h = h0 | (h1 << 16);
  l = (__builtin_bit_cast(uint32_t, r0) >> 16) |
      (__builtin_bit_cast(uint32_t, r1) & 0xFFFF0000u);
}

// ---- fused: zero W (64MB, raw f32) + transpose/split X -> Xh/Xl [N][K] bf16 ----
__global__ void zero_packX_kernel(uint4* __restrict__ W, const float* __restrict__ X,
                                  uint16_t* __restrict__ Xh, uint16_t* __restrict__ Xl) {
  unsigned bid = blockIdx.x;
  if (bid < 16384) {
    W[(size_t)bid * 256 + threadIdx.x] = make_uint4(0u, 0u, 0u, 0u);
    return;
  }
  bid -= 16384;
  __shared__ float t[32][33];
  int n0 = (bid & 63) * 32, k0 = (bid >> 6) * 32;
  int tx = threadIdx.x & 31, ty = threadIdx.x >> 5;  // 32 x 8
#pragma unroll
  for (int j = 0; j < 4; ++j)
    t[ty + j * 8][tx] = X[(size_t)(k0 + ty + j * 8) * NBAT + n0 + tx];
  __syncthreads();
#pragma unroll
  for (int j = 0; j < 4; ++j) {
    int n = n0 + ty + j * 8, k = k0 + tx;
    float f = t[tx][ty + j * 8];
    uint32_t hi = f2bf(f);
    float fhi = __builtin_bit_cast(float, hi << 16);
    uint32_t lo = f2bf(f - fhi);
    Xh[(size_t)n * INF + k] = (uint16_t)hi;
    Xl[(size_t)n * INF + k] = (uint16_t)lo;
  }
}

// ---- COO scatter-add (sums duplicates, matches .at[].add) ----
__global__ void scatter_kernel(const float* __restrict__ vals,
                               const int* __restrict__ rows,
                               const int* __restrict__ cols,
                               float* __restrict__ W, int nnz) {
  int i = blockIdx.x * blockDim.x + threadIdx.x;
  if (i < nnz) atomicAdd(&W[(size_t)rows[i] * INF + cols[i]], vals[i]);
}

// ---- split-bf16 GEMM: round-2 proven structure + counted-vmcnt double-buffer ---
// 4 waves (2x2), 128x128 tile, mi=ni=4, 16x16x32 MFMA, acc 64 regs (AGPR).
// A tile LDS: [128 rows][32 f32] = 128B/row (16KB), RAW W; hi/lo split in-reg.
// B tile LDS: [128 cols][2 planes][32 k] bf16 = 128B/row (16KB).
// 16B chunk c of row r lives at physical c ^ (r&7) (sources pre-swizzled,
// gload_lds dest linear - rule 21). Double-buffered 2x32KB; STAGE(t+2) issued
// after the buffer-free barrier; vmcnt(8) waits only t+1 (T4: never drain).
#define WAIT_VM(N) do { asm volatile("s_waitcnt vmcnt(" #N ")" ::: "memory"); } while (0)
#define BAR __builtin_amdgcn_s_barrier()

#define STAGE(BS) do { \
  _Pragma("unroll") for (int i = 0; i < 4; ++i) { \
    __builtin_amdgcn_global_load_lds((gptr_t)aSrc[i], \
        (lptr_t)(lds + (BS) * 32768 + i * 4096 + wid * 1024), 16, 0, 0); \
    aSrc[i] += 128; \
    __builtin_amdgcn_global_load_lds((gptr_t)bSrc[i], \
        (lptr_t)(lds + (BS) * 32768 + 16384 + i * 4096 + wid * 1024), 16, 0, 0); \
    bSrc[i] += 64; } \
} while (0)

__global__ __launch_bounds__(256, 2) void gemm_kernel(
    const float* __restrict__ Wr,      // [OUTF][INF] raw f32 (scatter output)
    const uint16_t* __restrict__ Xh,   // [NBAT][INF] bf16 bits
    const uint16_t* __restrict__ Xl,
    const float* __restrict__ bias,
    float* __restrict__ out) {         // [OUTF][NBAT]
  __shared__ __align__(16) uint8_t lds[65536];  // 2 x (16KB A + 16KB B)

  const unsigned tid = threadIdx.x;
  const unsigned lane = tid & 63, wid = tid >> 6;
  const unsigned wr = wid >> 1, wc = wid & 1;

  // bijective XCD swizzle (512 % 8 == 0): each XCD owns 2 bn panels (L2-fit X)
  unsigned newid = (blockIdx.x & 7) * 64 + (blockIdx.x >> 3);
  const unsigned bm = newid & 31, bn = newid >> 5;

  // staging sources (per-lane, pre-swizzled global addresses; LDS dest linear)
  const uint8_t* aSrc[4];
  const uint8_t* bSrc[4];
#pragma unroll
  for (int i = 0; i < 4; ++i) {
    unsigned d = i * 4096 + tid * 16;     // linear LDS byte this lane fills
    unsigned row = d >> 7;                // tile row (A) / tile col (B)
    unsigned ch = (d >> 4) & 7;           // 16B chunk within 128B row
    unsigned sc = ch ^ (row & 7);         // swizzled source chunk
    aSrc[i] = (const uint8_t*)Wr + (size_t)(bm * BM + row) * (INF * 4) + sc * 16;
    const uint16_t* base = (sc & 4) ? Xl : Xh;        // plane from swizzled chunk
    bSrc[i] = (const uint8_t*)(base + (size_t)(bn * BN + row) * INF + (sc & 3) * 8);
  }

  // kt-invariant fragment LDS byte offsets
  const unsigned kg = lane >> 4, lr = lane & 15;
  unsigned aOff[4][2], bOffH[4], bOffL[4];
#pragma unroll
  for (int mi = 0; mi < 4; ++mi) {
    unsigned row = wr * 64 + mi * 16 + lr;
    aOff[mi][0] = row * 128 + (((kg * 2 + 0) ^ (row & 7)) * 16);
    aOff[mi][1] = row * 128 + (((kg * 2 + 1) ^ (row & 7)) * 16);
  }
#pragma unroll
  for (int ni = 0; ni < 4; ++ni) {
    unsigned col = wc * 64 + ni * 16 + lr;
    bOffH[ni] = col * 128 + (((0 + kg) ^ (col & 7)) * 16);  // plane 0 (hi)
    bOffL[ni] = col * 128 + (((4 + kg) ^ (col & 7)) * 16);  // plane 1 (lo)
  }

  f32x4 acc[4][4] = {};

  // prologue: tiles 0,1 in flight; wait tile 0; make visible
  STAGE(0);
  STAGE(1);
  WAIT_VM(8);
  BAR;
  __builtin_amdgcn_sched_barrier(0);

  for (int t = 0; t < 128; ++t) {
    const unsigned bo = (t & 1) * 32768;

    // fragments for tile t (compiler inserts lgkmcnt before MFMA use)
    bf16x8 ah[4], al[4], bh[4], bl[4];
#pragma unroll
    for (int mi = 0; mi < 4; ++mi) {
      uint4 p0 = *(const uint4*)(lds + bo + aOff[mi][0]);
      uint4 p1 = *(const uint4*)(lds + bo + aOff[mi][1]);
      u32x4 h, l;
      uint32_t th, tl;
      split2(p0.x, p0.y, th, tl); h[0] = th; l[0] = tl;
      split2(p0.z, p0.w, th, tl); h[1] = th; l[1] = tl;
      split2(p1.x, p1.y, th, tl); h[2] = th; l[2] = tl;
      split2(p1.z, p1.w, th, tl); h[3] = th; l[3] = tl;
      ah[mi] = __builtin_bit_cast(bf16x8, h);
      al[mi] = __builtin_bit_cast(bf16x8, l);
    }
#pragma unroll
    for (int ni = 0; ni < 4; ++ni) {
      bh[ni] = *(const bf16x8*)(lds + bo + 16384 + bOffH[ni]);
      bl[ni] = *(const bf16x8*)(lds + bo + 16384 + bOffL[ni]);
    }

    __builtin_amdgcn_s_setprio(1);
#pragma unroll
    for (int mi = 0; mi < 4; ++mi)
#pragma unroll
      for (int ni = 0; ni < 4; ++ni) {
        acc[mi][ni] = __builtin_amdgcn_mfma_f32_16x16x32_bf16(ah[mi], bh[ni], acc[mi][ni], 0, 0, 0);
        acc[mi][ni] = __builtin_amdgcn_mfma_f32_16x16x32_bf16(ah[mi], bl[ni], acc[mi][ni], 0, 0, 0);
        acc[mi][ni] = __builtin_amdgcn_mfma_f32_16x16x32_bf16(al[mi], bh[ni], acc[mi][ni], 0, 0, 0);
      }
    __builtin_amdgcn_s_setprio(0);

    BAR;  // all waves done reading buffer t&1 -> free for tile t+2
    if (t < 126) {
      STAGE(t & 1);   // tile t+2 into freed buffer
      WAIT_VM(8);     // tile t+1 landed (t+2's 8 loads stay in flight)
    } else if (t == 126) {
      WAIT_VM(0);     // last tile: drain
    }
    if (t < 127) {
      BAR;            // tile t+1 visible to all waves
      __builtin_amdgcn_sched_barrier(0);  // keep next reads below this point
    }
  }

  // epilogue: C/D layout col=lane&15, row=4*(lane>>4)+reg (verified m89)
  const unsigned lq = lane >> 4;
#pragma unroll
  for (int mi = 0; mi < 4; ++mi) {
    unsigned row0 = bm * BM + wr * 64 + mi * 16 + lq * 4;
#pragma unroll
    for (int ni = 0; ni < 4; ++ni) {
      unsigned col = bn * BN + wc * 64 + ni * 16 + lr;
#pragma unroll
      for (int r = 0; r < 4; ++r)
        out[(size_t)(row0 + r) * NBAT + col] = acc[mi][ni][r] + bias[row0 + r];
    }
  }
}

extern "C" void kernel_launch(void* const* d_in, const int* in_sizes, int n_in,
                              void* d_out, int out_size, void* d_ws, size_t ws_size,
                              hipStream_t stream) {
  const float* inp    = (const float*)d_in[0];
  const float* values = (const float*)d_in[1];
  const float* bias   = (const float*)d_in[2];
  const int*   rows   = (const int*)d_in[3];
  const int*   cols   = (const int*)d_in[4];
  const int nnz = in_sizes[1];
  float* out = (float*)d_out;

  uint8_t* ws = (uint8_t*)d_ws;
  float*    W  = (float*)ws;                      // 64 MB raw f32 (GEMM reads directly)
  uint16_t* Xh = (uint16_t*)(ws + (64u << 20));   // 16 MB
  uint16_t* Xl = (uint16_t*)(ws + (80u << 20));   // 16 MB

  zero_packX_kernel<<<16384 + 8192, 256, 0, stream>>>((uint4*)W, inp, Xh, Xl);
  scatter_kernel<<<(nnz + 255) / 256, 256, 0, stream>>>(values, rows, cols, W, nnz);
  gemm_kernel<<<512, 256, 0, stream>>>(W, Xh, Xl, bias, out);
}